// Round 2
// baseline (1953.553 us; speedup 1.0000x reference)
//
#include <hip/hip_runtime.h>
#include <hip/hip_bf16.h>
#include <math.h>

#define NH 14
#define NKV 2
#define HD 64
#define HID 896
#define SEQ 2048
#define BATCH 2

// ---------------------------------------------------------------------------
// Kernel 1: fused QKV projection + bias + RoPE.
// X [4096, 896] fp32 @ W -> q/k/v fp32 in [b, head, s, d] layout.
// grid (Mtiles=64, Ntiles=18): ntile 0..13 -> Wq head h, 14..15 -> Wk, 16..17 -> Wv
// block (16,16); each thread computes a 4x4 micro-tile with 16-strided rows/cols
// so RoPE pairs (d, d+32) live in the same thread.
// ---------------------------------------------------------------------------
__global__ __launch_bounds__(256) void qkv_kernel(
    const float* __restrict__ X,
    const float* __restrict__ Wq, const float* __restrict__ bq,
    const float* __restrict__ Wk, const float* __restrict__ bk,
    const float* __restrict__ Wv, const float* __restrict__ bv,
    float* __restrict__ qbuf, float* __restrict__ kbuf, float* __restrict__ vbuf)
{
    __shared__ float As[64][33];
    __shared__ float Bs[32][65];
    const int tx = threadIdx.x, ty = threadIdx.y;
    const int tid = ty * 16 + tx;
    const int m0 = blockIdx.x * 64;
    const int nt = blockIdx.y;

    const float* W;
    const float* bias;
    int ldb, ncol0, kind;            // kind: 0=q, 1=k, 2=v
    if (nt < 14)      { W = Wq; bias = bq; ldb = HID;      ncol0 = nt * 64;        kind = 0; }
    else if (nt < 16) { W = Wk; bias = bk; ldb = NKV * HD; ncol0 = (nt - 14) * 64; kind = 1; }
    else              { W = Wv; bias = bv; ldb = NKV * HD; ncol0 = (nt - 16) * 64; kind = 2; }

    float acc[4][4] = {};

    for (int k0 = 0; k0 < HID; k0 += 32) {
        // A tile 64x32 (row-major contiguous in k)
        #pragma unroll
        for (int i = tid; i < 64 * 32; i += 256) {
            int r = i >> 5, c = i & 31;
            As[r][c] = X[(size_t)(m0 + r) * HID + k0 + c];
        }
        // B tile 32x64
        #pragma unroll
        for (int i = tid; i < 32 * 64; i += 256) {
            int r = i >> 6, c = i & 63;
            Bs[r][c] = W[(size_t)(k0 + r) * ldb + ncol0 + c];
        }
        __syncthreads();
        #pragma unroll
        for (int kk = 0; kk < 32; ++kk) {
            float a[4], bb[4];
            #pragma unroll
            for (int i = 0; i < 4; ++i) a[i] = As[ty + 16 * i][kk];
            #pragma unroll
            for (int j = 0; j < 4; ++j) bb[j] = Bs[kk][tx + 16 * j];
            #pragma unroll
            for (int i = 0; i < 4; ++i)
                #pragma unroll
                for (int j = 0; j < 4; ++j)
                    acc[i][j] += a[i] * bb[j];
        }
        __syncthreads();
    }

    // bias
    float bcol[4];
    #pragma unroll
    for (int j = 0; j < 4; ++j) bcol[j] = bias[ncol0 + tx + 16 * j];

    // inverse frequencies for this thread's dim pair columns (tx and tx+16, both < 32)
    const float lnth = 13.815510558f;  // ln(1e6)
    float if0 = expf(-((float)tx)        / 32.0f * lnth);
    float if1 = expf(-((float)(tx + 16)) / 32.0f * lnth);

    #pragma unroll
    for (int i = 0; i < 4; ++i) {
        int row = m0 + ty + 16 * i;
        int b = row >> 11;          // row / 2048
        int s = row & 2047;
        float v0 = acc[i][0] + bcol[0];
        float v1 = acc[i][1] + bcol[1];
        float v2 = acc[i][2] + bcol[2];
        float v3 = acc[i][3] + bcol[3];
        if (kind != 2) {
            float s0, c0, s1, c1;
            sincosf((float)s * if0, &s0, &c0);
            sincosf((float)s * if1, &s1, &c1);
            float n0 = v0 * c0 - v2 * s0;
            float n2 = v2 * c0 + v0 * s0;
            float n1 = v1 * c1 - v3 * s1;
            float n3 = v3 * c1 + v1 * s1;
            v0 = n0; v1 = n1; v2 = n2; v3 = n3;
        }
        float* dst;
        if (kind == 0) {
            dst = qbuf + (((size_t)b * NH + nt) * SEQ + s) * HD;
        } else {
            int kvh = (kind == 1) ? (nt - 14) : (nt - 16);
            dst = ((kind == 1) ? kbuf : vbuf) + (((size_t)b * NKV + kvh) * SEQ + s) * HD;
        }
        dst[tx]      = v0;
        dst[tx + 16] = v1;
        dst[tx + 32] = v2;
        dst[tx + 48] = v3;
    }
}

// ---------------------------------------------------------------------------
// Kernel 2: causal flash attention.
// grid (S/64=32, NH=14, B=2), block = 64 (one wave). One thread per Q row;
// K/V staged in LDS in 64-key tiles; online softmax in registers.
// ---------------------------------------------------------------------------
__global__ __launch_bounds__(64) void attn_kernel(
    const float* __restrict__ qbuf, const float* __restrict__ kbuf,
    const float* __restrict__ vbuf, float* __restrict__ abuf)
{
    __shared__ float Ks[64 * 64];
    __shared__ float Vs[64 * 64];
    const int tid = threadIdx.x;
    const int qt = blockIdx.x;
    const int h  = blockIdx.y;
    const int b  = blockIdx.z;
    const int kvh = h / (NH / NKV);
    const int row = qt * 64 + tid;

    const float* qp = qbuf + (((size_t)b * NH + h) * SEQ + row) * HD;
    float q[64];
    #pragma unroll
    for (int d = 0; d < 64; ++d) q[d] = qp[d] * 0.125f;   // 1/sqrt(64)

    float m_i = -1e30f, l_i = 0.0f;
    float o[64];
    #pragma unroll
    for (int d = 0; d < 64; ++d) o[d] = 0.0f;

    const float* kbase = kbuf + ((size_t)b * NKV + kvh) * SEQ * HD;
    const float* vbase = vbuf + ((size_t)b * NKV + kvh) * SEQ * HD;

    for (int kt = 0; kt <= qt; ++kt) {
        for (int i = tid; i < 64 * 64; i += 64) {
            Ks[i] = kbase[(size_t)kt * 64 * 64 + i];
            Vs[i] = vbase[(size_t)kt * 64 * 64 + i];
        }
        __syncthreads();

        float sc[64];
        float tmax = -1e30f;
        const bool diag = (kt == qt);
        for (int k = 0; k < 64; ++k) {
            const float4* kp = (const float4*)&Ks[k * 64];
            float dot = 0.0f;
            #pragma unroll
            for (int d4 = 0; d4 < 16; ++d4) {
                float4 kv = kp[d4];
                dot += q[4 * d4 + 0] * kv.x + q[4 * d4 + 1] * kv.y +
                       q[4 * d4 + 2] * kv.z + q[4 * d4 + 3] * kv.w;
            }
            if (diag && k > tid) dot = -1e30f;
            sc[k] = dot;
            tmax = fmaxf(tmax, dot);
        }

        float m_new = fmaxf(m_i, tmax);
        float alpha = __expf(m_i - m_new);
        l_i *= alpha;
        #pragma unroll
        for (int d = 0; d < 64; ++d) o[d] *= alpha;

        for (int k = 0; k < 64; ++k) {
            float p = __expf(sc[k] - m_new);
            l_i += p;
            const float4* vp = (const float4*)&Vs[k * 64];
            #pragma unroll
            for (int d4 = 0; d4 < 16; ++d4) {
                float4 vv = vp[d4];
                o[4 * d4 + 0] += p * vv.x;
                o[4 * d4 + 1] += p * vv.y;
                o[4 * d4 + 2] += p * vv.z;
                o[4 * d4 + 3] += p * vv.w;
            }
        }
        m_i = m_new;
        __syncthreads();
    }

    float inv = 1.0f / l_i;
    float* op = abuf + ((size_t)(b * SEQ + row)) * (NH * HD) + h * HD;
    #pragma unroll
    for (int d = 0; d < 64; ++d) op[d] = o[d] * inv;
}

// ---------------------------------------------------------------------------
// Kernel 3: output projection. abuf [4096, 896] fp32 @ Wo [896, 896] fp32
// -> out fp32 [4096, 896]. Same tiling as kernel 1, no bias/rope.
// ---------------------------------------------------------------------------
__global__ __launch_bounds__(256) void oproj_kernel(
    const float* __restrict__ A, const float* __restrict__ Wo,
    float* __restrict__ out)
{
    __shared__ float As[64][33];
    __shared__ float Bs[32][65];
    const int tx = threadIdx.x, ty = threadIdx.y;
    const int tid = ty * 16 + tx;
    const int m0 = blockIdx.x * 64;
    const int n0 = blockIdx.y * 64;

    float acc[4][4] = {};

    for (int k0 = 0; k0 < HID; k0 += 32) {
        #pragma unroll
        for (int i = tid; i < 64 * 32; i += 256) {
            int r = i >> 5, c = i & 31;
            As[r][c] = A[(size_t)(m0 + r) * HID + k0 + c];
        }
        #pragma unroll
        for (int i = tid; i < 32 * 64; i += 256) {
            int r = i >> 6, c = i & 63;
            Bs[r][c] = Wo[(size_t)(k0 + r) * HID + n0 + c];
        }
        __syncthreads();
        #pragma unroll
        for (int kk = 0; kk < 32; ++kk) {
            float a[4], bb[4];
            #pragma unroll
            for (int i = 0; i < 4; ++i) a[i] = As[ty + 16 * i][kk];
            #pragma unroll
            for (int j = 0; j < 4; ++j) bb[j] = Bs[kk][tx + 16 * j];
            #pragma unroll
            for (int i = 0; i < 4; ++i)
                #pragma unroll
                for (int j = 0; j < 4; ++j)
                    acc[i][j] += a[i] * bb[j];
        }
        __syncthreads();
    }

    #pragma unroll
    for (int i = 0; i < 4; ++i) {
        size_t rbase = (size_t)(m0 + ty + 16 * i) * HID + n0;
        #pragma unroll
        for (int j = 0; j < 4; ++j)
            out[rbase + tx + 16 * j] = acc[i][j];
    }
}

extern "C" void kernel_launch(void* const* d_in, const int* in_sizes, int n_in,
                              void* d_out, int out_size, void* d_ws, size_t ws_size,
                              hipStream_t stream) {
    const float* X  = (const float*)d_in[0];
    // d_in[1] = attention_mask: exactly the causal mask; applied analytically.
    const float* Wq = (const float*)d_in[2];
    const float* bq = (const float*)d_in[3];
    const float* Wk = (const float*)d_in[4];
    const float* bk = (const float*)d_in[5];
    const float* Wv = (const float*)d_in[6];
    const float* bv = (const float*)d_in[7];
    const float* Wo = (const float*)d_in[8];
    float* out = (float*)d_out;

    float* ws = (float*)d_ws;
    float* qbuf = ws;                                   // 2*14*2048*64 = 3,670,016
    float* kbuf = qbuf + (size_t)BATCH * NH * SEQ * HD; //   524,288
    float* vbuf = kbuf + (size_t)BATCH * NKV * SEQ * HD;
    float* abuf = vbuf + (size_t)BATCH * NKV * SEQ * HD; // 3,670,016
    // total = 32 MB fp32

    qkv_kernel<<<dim3(64, 18), dim3(16, 16), 0, stream>>>(
        X, Wq, bq, Wk, bk, Wv, bv, qbuf, kbuf, vbuf);
    attn_kernel<<<dim3(SEQ / 64, NH, BATCH), 64, 0, stream>>>(
        qbuf, kbuf, vbuf, abuf);
    oproj_kernel<<<dim3(64, 14), dim3(16, 16), 0, stream>>>(
        abuf, Wo, out);
}

// Round 3
// 1551.829 us; speedup vs baseline: 1.2589x; 1.2589x over previous
//
#include <hip/hip_runtime.h>
#include <hip/hip_bf16.h>
#include <math.h>

#define NH 14
#define NKV 2
#define HD 64
#define HID 896
#define SEQ 2048
#define BATCH 2

// ---------------------------------------------------------------------------
// Kernel 1: fused QKV projection + bias + RoPE.
// X [4096, 896] fp32 @ W -> q/k/v fp32 in [b, head, s, d] layout.
// grid (64, 18): ntile 0..13 -> Wq head, 14..15 -> Wk, 16..17 -> Wv.
// block (16,16). Thread owns rows ty*4..ty*4+3 (contiguous -> ds_read_b128 on
// k-major A tile) and cols tx+{0,16,32,48} (strided so RoPE pair (d,d+32) is
// in-thread).
// ---------------------------------------------------------------------------
__global__ __launch_bounds__(256) void qkv_kernel(
    const float* __restrict__ X,
    const float* __restrict__ Wq, const float* __restrict__ bq,
    const float* __restrict__ Wk, const float* __restrict__ bk,
    const float* __restrict__ Wv, const float* __restrict__ bv,
    float* __restrict__ qbuf, float* __restrict__ kbuf, float* __restrict__ vbuf)
{
    __shared__ float At[32][65];   // k-major: At[k][m]
    __shared__ float Bs[32][65];   // Bs[k][n]
    const int tx = threadIdx.x, ty = threadIdx.y;
    const int tid = ty * 16 + tx;
    const int m0 = blockIdx.x * 64;
    const int nt = blockIdx.y;

    const float* W;
    const float* bias;
    int ldb, ncol0, kind;            // 0=q, 1=k, 2=v
    if (nt < 14)      { W = Wq; bias = bq; ldb = HID;      ncol0 = nt * 64;        kind = 0; }
    else if (nt < 16) { W = Wk; bias = bk; ldb = NKV * HD; ncol0 = (nt - 14) * 64; kind = 1; }
    else              { W = Wv; bias = bv; ldb = NKV * HD; ncol0 = (nt - 16) * 64; kind = 2; }

    float acc[4][4] = {};

    for (int k0 = 0; k0 < HID; k0 += 32) {
        #pragma unroll
        for (int i = tid; i < 64 * 32; i += 256) {
            int r = i >> 5, c = i & 31;                      // c consecutive per lane
            At[c][r] = X[(size_t)(m0 + r) * HID + k0 + c];
        }
        #pragma unroll
        for (int i = tid; i < 32 * 64; i += 256) {
            int r = i >> 6, c = i & 63;
            Bs[r][c] = W[(size_t)(k0 + r) * ldb + ncol0 + c];
        }
        __syncthreads();
        #pragma unroll
        for (int kk = 0; kk < 32; ++kk) {
            float4 av = *(const float4*)&At[kk][ty * 4];
            float a[4] = {av.x, av.y, av.z, av.w};
            float bb[4];
            #pragma unroll
            for (int j = 0; j < 4; ++j) bb[j] = Bs[kk][tx + 16 * j];
            #pragma unroll
            for (int i = 0; i < 4; ++i)
                #pragma unroll
                for (int j = 0; j < 4; ++j)
                    acc[i][j] += a[i] * bb[j];
        }
        __syncthreads();
    }

    float bcol[4];
    #pragma unroll
    for (int j = 0; j < 4; ++j) bcol[j] = bias[ncol0 + tx + 16 * j];

    const float lnth = 13.815510558f;  // ln(1e6)
    float if0 = expf(-((float)tx)        / 32.0f * lnth);
    float if1 = expf(-((float)(tx + 16)) / 32.0f * lnth);

    #pragma unroll
    for (int i = 0; i < 4; ++i) {
        int row = m0 + ty * 4 + i;
        int b = row >> 11;
        int s = row & 2047;
        float v0 = acc[i][0] + bcol[0];
        float v1 = acc[i][1] + bcol[1];
        float v2 = acc[i][2] + bcol[2];
        float v3 = acc[i][3] + bcol[3];
        if (kind != 2) {
            float s0, c0, s1, c1;
            sincosf((float)s * if0, &s0, &c0);
            sincosf((float)s * if1, &s1, &c1);
            float n0 = v0 * c0 - v2 * s0;
            float n2 = v2 * c0 + v0 * s0;
            float n1 = v1 * c1 - v3 * s1;
            float n3 = v3 * c1 + v1 * s1;
            v0 = n0; v1 = n1; v2 = n2; v3 = n3;
        }
        float* dst;
        if (kind == 0) {
            dst = qbuf + (((size_t)b * NH + nt) * SEQ + s) * HD;
        } else {
            int kvh = (kind == 1) ? (nt - 14) : (nt - 16);
            dst = ((kind == 1) ? kbuf : vbuf) + (((size_t)b * NKV + kvh) * SEQ + s) * HD;
        }
        dst[tx]      = v0;
        dst[tx + 16] = v1;
        dst[tx + 32] = v2;
        dst[tx + 48] = v3;
    }
}

// ---------------------------------------------------------------------------
// Kernel 2: causal flash attention, split-D.
// grid (S/64=32, NH, B), block 256 (4 waves). Wave w owns Q rows w*16..w*16+15;
// lane = (row&15)*4 + quarter; each thread holds 16 dims (quarter*16..+15).
// Full QK dot via shfl_xor(1)+shfl_xor(2) within the lane-quad (same row).
// Online softmax in 16-key chunks; no spills (live set ~50 floats).
// ---------------------------------------------------------------------------
__global__ __launch_bounds__(256) void attn_kernel(
    const float* __restrict__ qbuf, const float* __restrict__ kbuf,
    const float* __restrict__ vbuf, float* __restrict__ abuf)
{
    __shared__ float Ks[64 * 64];
    __shared__ float Vs[64 * 64];
    const int tid = threadIdx.x;
    const int w = tid >> 6;
    const int lane = tid & 63;
    const int rit = w * 16 + (lane >> 2);   // row in 64-row tile
    const int quarter = lane & 3;
    const int qt = blockIdx.x;
    const int h  = blockIdx.y;
    const int b  = blockIdx.z;
    const int kvh = h / (NH / NKV);
    const int rowg = qt * 64 + rit;

    const float* qp = qbuf + (((size_t)b * NH + h) * SEQ + rowg) * HD + quarter * 16;
    float q[16];
    #pragma unroll
    for (int g = 0; g < 4; ++g) {
        float4 v = ((const float4*)qp)[g];
        q[4*g+0] = v.x * 0.125f; q[4*g+1] = v.y * 0.125f;
        q[4*g+2] = v.z * 0.125f; q[4*g+3] = v.w * 0.125f;
    }

    float m_i = -1e30f, l_i = 0.0f;
    float o[16];
    #pragma unroll
    for (int d = 0; d < 16; ++d) o[d] = 0.0f;

    const float* kbase = kbuf + ((size_t)b * NKV + kvh) * SEQ * HD;
    const float* vbase = vbuf + ((size_t)b * NKV + kvh) * SEQ * HD;

    for (int kt = 0; kt <= qt; ++kt) {
        const float4* ksrc = (const float4*)(kbase + (size_t)kt * 64 * 64);
        const float4* vsrc = (const float4*)(vbase + (size_t)kt * 64 * 64);
        for (int i = tid; i < 1024; i += 256) {
            ((float4*)Ks)[i] = ksrc[i];
            ((float4*)Vs)[i] = vsrc[i];
        }
        __syncthreads();

        const bool diag = (kt == qt);
        for (int c0 = 0; c0 < 64; c0 += 16) {
            if (diag && c0 > rit) break;   // quad-uniform: all 4 lanes share rit
            float sc[16];
            float cmax = -1e30f;
            #pragma unroll
            for (int j = 0; j < 16; ++j) {
                const int k = c0 + j;
                const float4* kp = (const float4*)&Ks[k * 64 + quarter * 16];
                float dot = 0.0f;
                #pragma unroll
                for (int g = 0; g < 4; ++g) {
                    float4 kv = kp[g];
                    dot += q[4*g+0] * kv.x + q[4*g+1] * kv.y +
                           q[4*g+2] * kv.z + q[4*g+3] * kv.w;
                }
                dot += __shfl_xor(dot, 1);
                dot += __shfl_xor(dot, 2);
                if (diag && k > rit) dot = -1e30f;
                sc[j] = dot;
                cmax = fmaxf(cmax, dot);
            }
            float m_new = fmaxf(m_i, cmax);
            float alpha = __expf(m_i - m_new);
            l_i *= alpha;
            #pragma unroll
            for (int d = 0; d < 16; ++d) o[d] *= alpha;
            #pragma unroll
            for (int j = 0; j < 16; ++j) {
                float p = __expf(sc[j] - m_new);
                l_i += p;
                const float4* vp = (const float4*)&Vs[(c0 + j) * 64 + quarter * 16];
                #pragma unroll
                for (int g = 0; g < 4; ++g) {
                    float4 vv = vp[g];
                    o[4*g+0] += p * vv.x; o[4*g+1] += p * vv.y;
                    o[4*g+2] += p * vv.z; o[4*g+3] += p * vv.w;
                }
            }
            m_i = m_new;
        }
        __syncthreads();
    }

    float inv = 1.0f / l_i;
    float* op = abuf + ((size_t)(b * SEQ + rowg)) * (NH * HD) + h * HD + quarter * 16;
    #pragma unroll
    for (int g = 0; g < 4; ++g) {
        float4 v;
        v.x = o[4*g+0] * inv; v.y = o[4*g+1] * inv;
        v.z = o[4*g+2] * inv; v.w = o[4*g+3] * inv;
        ((float4*)op)[g] = v;
    }
}

// ---------------------------------------------------------------------------
// Kernel 3: output projection. abuf [4096,896] @ Wo [896,896] -> out fp32.
// Fully vectorized LDS reads (k-major A, contiguous B cols) + float4 stores.
// ---------------------------------------------------------------------------
__global__ __launch_bounds__(256) void oproj_kernel(
    const float* __restrict__ A, const float* __restrict__ Wo,
    float* __restrict__ out)
{
    __shared__ float At[32][65];
    __shared__ float Bs[32][65];
    const int tx = threadIdx.x, ty = threadIdx.y;
    const int tid = ty * 16 + tx;
    const int m0 = blockIdx.x * 64;
    const int n0 = blockIdx.y * 64;

    float acc[4][4] = {};

    for (int k0 = 0; k0 < HID; k0 += 32) {
        #pragma unroll
        for (int i = tid; i < 64 * 32; i += 256) {
            int r = i >> 5, c = i & 31;
            At[c][r] = A[(size_t)(m0 + r) * HID + k0 + c];
        }
        #pragma unroll
        for (int i = tid; i < 32 * 64; i += 256) {
            int r = i >> 6, c = i & 63;
            Bs[r][c] = Wo[(size_t)(k0 + r) * HID + n0 + c];
        }
        __syncthreads();
        #pragma unroll
        for (int kk = 0; kk < 32; ++kk) {
            float4 av = *(const float4*)&At[kk][ty * 4];
            float4 bv = *(const float4*)&Bs[kk][tx * 4];
            float a[4] = {av.x, av.y, av.z, av.w};
            float bb[4] = {bv.x, bv.y, bv.z, bv.w};
            #pragma unroll
            for (int i = 0; i < 4; ++i)
                #pragma unroll
                for (int j = 0; j < 4; ++j)
                    acc[i][j] += a[i] * bb[j];
        }
        __syncthreads();
    }

    #pragma unroll
    for (int i = 0; i < 4; ++i) {
        size_t rbase = (size_t)(m0 + ty * 4 + i) * HID + n0;
        float4 v;
        v.x = acc[i][0]; v.y = acc[i][1]; v.z = acc[i][2]; v.w = acc[i][3];
        *(float4*)&out[rbase + tx * 4] = v;
    }
}

extern "C" void kernel_launch(void* const* d_in, const int* in_sizes, int n_in,
                              void* d_out, int out_size, void* d_ws, size_t ws_size,
                              hipStream_t stream) {
    const float* X  = (const float*)d_in[0];
    // d_in[1] = attention_mask: exactly causal; applied analytically.
    const float* Wq = (const float*)d_in[2];
    const float* bq = (const float*)d_in[3];
    const float* Wk = (const float*)d_in[4];
    const float* bk = (const float*)d_in[5];
    const float* Wv = (const float*)d_in[6];
    const float* bv = (const float*)d_in[7];
    const float* Wo = (const float*)d_in[8];
    float* out = (float*)d_out;

    float* ws = (float*)d_ws;
    float* qbuf = ws;
    float* kbuf = qbuf + (size_t)BATCH * NH * SEQ * HD;
    float* vbuf = kbuf + (size_t)BATCH * NKV * SEQ * HD;
    float* abuf = vbuf + (size_t)BATCH * NKV * SEQ * HD;

    qkv_kernel<<<dim3(64, 18), dim3(16, 16), 0, stream>>>(
        X, Wq, bq, Wk, bk, Wv, bv, qbuf, kbuf, vbuf);
    attn_kernel<<<dim3(SEQ / 64, NH, BATCH), 256, 0, stream>>>(
        qbuf, kbuf, vbuf, abuf);
    oproj_kernel<<<dim3(64, 14), dim3(16, 16), 0, stream>>>(
        abuf, Wo, out);
}

// Round 4
// 760.790 us; speedup vs baseline: 2.5678x; 2.0398x over previous
//
#include <hip/hip_runtime.h>
#include <hip/hip_bf16.h>
#include <math.h>

#define NH 14
#define NKV 2
#define HD 64
#define HID 896
#define SEQ 2048
#define BATCH 2

typedef __attribute__((ext_vector_type(8))) short short8;
typedef __attribute__((ext_vector_type(4))) float f32x4;
typedef unsigned short ushort_t;

__device__ __forceinline__ unsigned short f2b(float f) {
    unsigned int u = __float_as_uint(f);
    unsigned int r = (u + 0x7fffu + ((u >> 16) & 1u)) >> 16;   // RNE
    return (unsigned short)r;
}

// ---------------------------------------------------------------------------
// Kernel 1: fused QKV projection + bias + RoPE. fp32 compute; outputs bf16.
// qbuf [b][h][s][d], kbuf [b][kvh][s][d], vbuf TRANSPOSED [b][kvh][d][s].
// ---------------------------------------------------------------------------
__global__ __launch_bounds__(256) void qkv_kernel(
    const float* __restrict__ X,
    const float* __restrict__ Wq, const float* __restrict__ bq,
    const float* __restrict__ Wk, const float* __restrict__ bk,
    const float* __restrict__ Wv, const float* __restrict__ bv,
    ushort_t* __restrict__ qbuf, ushort_t* __restrict__ kbuf,
    ushort_t* __restrict__ vbuf)
{
    __shared__ float At[32][65];   // k-major: At[k][m]
    __shared__ float Bs[32][65];
    const int tx = threadIdx.x, ty = threadIdx.y;
    const int tid = ty * 16 + tx;
    const int m0 = blockIdx.x * 64;
    const int nt = blockIdx.y;

    const float* W;
    const float* bias;
    int ldb, ncol0, kind;            // 0=q, 1=k, 2=v
    if (nt < 14)      { W = Wq; bias = bq; ldb = HID;      ncol0 = nt * 64;        kind = 0; }
    else if (nt < 16) { W = Wk; bias = bk; ldb = NKV * HD; ncol0 = (nt - 14) * 64; kind = 1; }
    else              { W = Wv; bias = bv; ldb = NKV * HD; ncol0 = (nt - 16) * 64; kind = 2; }

    float acc[4][4] = {};

    for (int k0 = 0; k0 < HID; k0 += 32) {
        #pragma unroll
        for (int i = tid; i < 64 * 32; i += 256) {
            int r = i >> 5, c = i & 31;
            At[c][r] = X[(size_t)(m0 + r) * HID + k0 + c];
        }
        #pragma unroll
        for (int i = tid; i < 32 * 64; i += 256) {
            int r = i >> 6, c = i & 63;
            Bs[r][c] = W[(size_t)(k0 + r) * ldb + ncol0 + c];
        }
        __syncthreads();
        #pragma unroll
        for (int kk = 0; kk < 32; ++kk) {
            float4 av = *(const float4*)&At[kk][ty * 4];
            float a[4] = {av.x, av.y, av.z, av.w};
            float bb[4];
            #pragma unroll
            for (int j = 0; j < 4; ++j) bb[j] = Bs[kk][tx + 16 * j];
            #pragma unroll
            for (int i = 0; i < 4; ++i)
                #pragma unroll
                for (int j = 0; j < 4; ++j)
                    acc[i][j] += a[i] * bb[j];
        }
        __syncthreads();
    }

    float bcol[4];
    #pragma unroll
    for (int j = 0; j < 4; ++j) bcol[j] = bias[ncol0 + tx + 16 * j];

    const float lnth = 13.815510558f;  // ln(1e6)
    float if0 = expf(-((float)tx)        / 32.0f * lnth);
    float if1 = expf(-((float)(tx + 16)) / 32.0f * lnth);

    #pragma unroll
    for (int i = 0; i < 4; ++i) {
        int row = m0 + ty * 4 + i;
        int b = row >> 11;
        int s = row & 2047;
        float v0 = acc[i][0] + bcol[0];
        float v1 = acc[i][1] + bcol[1];
        float v2 = acc[i][2] + bcol[2];
        float v3 = acc[i][3] + bcol[3];
        if (kind != 2) {
            float s0, c0, s1, c1;
            sincosf((float)s * if0, &s0, &c0);
            sincosf((float)s * if1, &s1, &c1);
            float n0 = v0 * c0 - v2 * s0;
            float n2 = v2 * c0 + v0 * s0;
            float n1 = v1 * c1 - v3 * s1;
            float n3 = v3 * c1 + v1 * s1;
            v0 = n0; v1 = n1; v2 = n2; v3 = n3;
        }
        if (kind == 0) {
            ushort_t* dst = qbuf + (((size_t)b * NH + nt) * SEQ + s) * HD;
            dst[tx]      = f2b(v0);
            dst[tx + 16] = f2b(v1);
            dst[tx + 32] = f2b(v2);
            dst[tx + 48] = f2b(v3);
        } else if (kind == 1) {
            int kvh = nt - 14;
            ushort_t* dst = kbuf + (((size_t)b * NKV + kvh) * SEQ + s) * HD;
            dst[tx]      = f2b(v0);
            dst[tx + 16] = f2b(v1);
            dst[tx + 32] = f2b(v2);
            dst[tx + 48] = f2b(v3);
        } else {
            int kvh = nt - 16;
            ushort_t* dst = vbuf + ((size_t)b * NKV + kvh) * HD * SEQ + s;
            dst[(size_t)(tx)      * SEQ] = f2b(v0);
            dst[(size_t)(tx + 16) * SEQ] = f2b(v1);
            dst[(size_t)(tx + 32) * SEQ] = f2b(v2);
            dst[(size_t)(tx + 48) * SEQ] = f2b(v3);
        }
    }
}

// ---------------------------------------------------------------------------
// Kernel 2: causal flash attention via bf16 MFMA 16x16x32.
// grid (16, NH, B), 256 threads = 4 waves. Block bi does q-tiles bi and 31-bi
// (uniform 33 key-tile iterations). Wave w owns 16 q-rows.
// LDS stride 72 elements (144 B: 16B-aligned, bank-swizzled).
// ---------------------------------------------------------------------------
#define LDP 72
__global__ __launch_bounds__(256) void attn_kernel(
    const ushort_t* __restrict__ qbuf, const ushort_t* __restrict__ kbuf,
    const ushort_t* __restrict__ vbuf, float* __restrict__ abuf)
{
    __shared__ ushort_t Ks[64 * LDP];
    __shared__ ushort_t Vt[64 * LDP];
    __shared__ ushort_t Ps[4][16 * LDP];

    const int tid  = threadIdx.x;
    const int w    = tid >> 6;
    const int lane = tid & 63;
    const int quad = lane >> 4;
    const int l16  = lane & 15;
    const int bi = blockIdx.x;
    const int h  = blockIdx.y;
    const int b  = blockIdx.z;
    const int kvh = h / (NH / NKV);

    const ushort_t* kb_h = kbuf + (size_t)(b * NKV + kvh) * SEQ * HD;
    const ushort_t* vt_h = vbuf + (size_t)(b * NKV + kvh) * HD * SEQ;

    for (int pass = 0; pass < 2; ++pass) {
        const int qt = pass ? (31 - bi) : bi;

        // Q A-fragments straight from global (2 chunks of K=32)
        const ushort_t* qrow =
            qbuf + ((size_t)((b * NH + h) * SEQ) + qt * 64 + w * 16 + l16) * HD;
        short8 qf0 = *(const short8*)(qrow + quad * 8);
        short8 qf1 = *(const short8*)(qrow + 32 + quad * 8);

        f32x4 O[4];
        float m_i[4], l_i[4];
        #pragma unroll
        for (int n = 0; n < 4; ++n) O[n] = (f32x4){0.f, 0.f, 0.f, 0.f};
        #pragma unroll
        for (int r = 0; r < 4; ++r) { m_i[r] = -1e30f; l_i[r] = 0.0f; }

        for (int kt = 0; kt <= qt; ++kt) {
            __syncthreads();   // previous tile fully consumed
            for (int i = tid; i < 512; i += 256) {
                int row = i >> 3, c8 = i & 7;
                *(uint4*)&Ks[row * LDP + c8 * 8] =
                    *(const uint4*)(kb_h + ((size_t)(kt * 64 + row)) * HD + c8 * 8);
                *(uint4*)&Vt[row * LDP + c8 * 8] =
                    *(const uint4*)(vt_h + (size_t)row * SEQ + kt * 64 + c8 * 8);
            }
            __syncthreads();

            // QK^T: 4 key-fragments x 2 K-chunks
            f32x4 S[4];
            #pragma unroll
            for (int f = 0; f < 4; ++f) {
                S[f] = (f32x4){0.f, 0.f, 0.f, 0.f};
                short8 kf0 = *(const short8*)&Ks[(f * 16 + l16) * LDP + quad * 8];
                short8 kf1 = *(const short8*)&Ks[(f * 16 + l16) * LDP + 32 + quad * 8];
                S[f] = __builtin_amdgcn_mfma_f32_16x16x32_bf16(qf0, kf0, S[f], 0, 0, 0);
                S[f] = __builtin_amdgcn_mfma_f32_16x16x32_bf16(qf1, kf1, S[f], 0, 0, 0);
            }

            const bool diag = (kt == qt);
            float sc[4][4];
            #pragma unroll
            for (int f = 0; f < 4; ++f)
                #pragma unroll
                for (int r = 0; r < 4; ++r) {
                    float v = S[f][r] * 0.125f;
                    if (diag && (f * 16 + l16) > (w * 16 + quad * 4 + r)) v = -1e30f;
                    sc[f][r] = v;
                }

            float pm[4];
            #pragma unroll
            for (int r = 0; r < 4; ++r)
                pm[r] = fmaxf(fmaxf(sc[0][r], sc[1][r]), fmaxf(sc[2][r], sc[3][r]));
            #pragma unroll
            for (int off = 1; off < 16; off <<= 1)
                #pragma unroll
                for (int r = 0; r < 4; ++r)
                    pm[r] = fmaxf(pm[r], __shfl_xor(pm[r], off));

            float alpha[4], psum[4];
            #pragma unroll
            for (int r = 0; r < 4; ++r) {
                float mnew = fmaxf(m_i[r], pm[r]);
                alpha[r] = __expf(m_i[r] - mnew);
                m_i[r] = mnew;
                psum[r] = 0.0f;
            }
            #pragma unroll
            for (int f = 0; f < 4; ++f)
                #pragma unroll
                for (int r = 0; r < 4; ++r) {
                    float p = __expf(sc[f][r] - m_i[r]);
                    sc[f][r] = p;
                    psum[r] += p;
                }
            #pragma unroll
            for (int off = 1; off < 16; off <<= 1)
                #pragma unroll
                for (int r = 0; r < 4; ++r)
                    psum[r] += __shfl_xor(psum[r], off);
            #pragma unroll
            for (int r = 0; r < 4; ++r)
                l_i[r] = l_i[r] * alpha[r] + psum[r];
            #pragma unroll
            for (int n = 0; n < 4; ++n)
                #pragma unroll
                for (int r = 0; r < 4; ++r)
                    O[n][r] *= alpha[r];

            // P: C-layout -> LDS -> A-layout (per-wave buffer)
            #pragma unroll
            for (int f = 0; f < 4; ++f)
                #pragma unroll
                for (int r = 0; r < 4; ++r)
                    Ps[w][(quad * 4 + r) * LDP + f * 16 + l16] = f2b(sc[f][r]);
            short8 pa0 = *(const short8*)&Ps[w][l16 * LDP + quad * 8];
            short8 pa1 = *(const short8*)&Ps[w][l16 * LDP + 32 + quad * 8];

            // PV: 4 dim-fragments x 2 key-chunks
            #pragma unroll
            for (int n = 0; n < 4; ++n) {
                short8 vf0 = *(const short8*)&Vt[(n * 16 + l16) * LDP + quad * 8];
                short8 vf1 = *(const short8*)&Vt[(n * 16 + l16) * LDP + 32 + quad * 8];
                O[n] = __builtin_amdgcn_mfma_f32_16x16x32_bf16(pa0, vf0, O[n], 0, 0, 0);
                O[n] = __builtin_amdgcn_mfma_f32_16x16x32_bf16(pa1, vf1, O[n], 0, 0, 0);
            }
        }

        float inv[4];
        #pragma unroll
        for (int r = 0; r < 4; ++r) inv[r] = 1.0f / l_i[r];
        #pragma unroll
        for (int n = 0; n < 4; ++n)
            #pragma unroll
            for (int r = 0; r < 4; ++r) {
                int rowg = qt * 64 + w * 16 + quad * 4 + r;
                abuf[((size_t)(b * SEQ + rowg)) * (NH * HD) + h * HD + n * 16 + l16]
                    = O[n][r] * inv[r];
            }
    }
}

// ---------------------------------------------------------------------------
// Kernel 3: output projection (fp32 VALU, unchanged).
// ---------------------------------------------------------------------------
__global__ __launch_bounds__(256) void oproj_kernel(
    const float* __restrict__ A, const float* __restrict__ Wo,
    float* __restrict__ out)
{
    __shared__ float At[32][65];
    __shared__ float Bs[32][65];
    const int tx = threadIdx.x, ty = threadIdx.y;
    const int tid = ty * 16 + tx;
    const int m0 = blockIdx.x * 64;
    const int n0 = blockIdx.y * 64;

    float acc[4][4] = {};

    for (int k0 = 0; k0 < HID; k0 += 32) {
        #pragma unroll
        for (int i = tid; i < 64 * 32; i += 256) {
            int r = i >> 5, c = i & 31;
            At[c][r] = A[(size_t)(m0 + r) * HID + k0 + c];
        }
        #pragma unroll
        for (int i = tid; i < 32 * 64; i += 256) {
            int r = i >> 6, c = i & 63;
            Bs[r][c] = Wo[(size_t)(k0 + r) * HID + n0 + c];
        }
        __syncthreads();
        #pragma unroll
        for (int kk = 0; kk < 32; ++kk) {
            float4 av = *(const float4*)&At[kk][ty * 4];
            float4 bv = *(const float4*)&Bs[kk][tx * 4];
            float a[4] = {av.x, av.y, av.z, av.w};
            float bb[4] = {bv.x, bv.y, bv.z, bv.w};
            #pragma unroll
            for (int i = 0; i < 4; ++i)
                #pragma unroll
                for (int j = 0; j < 4; ++j)
                    acc[i][j] += a[i] * bb[j];
        }
        __syncthreads();
    }

    #pragma unroll
    for (int i = 0; i < 4; ++i) {
        size_t rbase = (size_t)(m0 + ty * 4 + i) * HID + n0;
        float4 v;
        v.x = acc[i][0]; v.y = acc[i][1]; v.z = acc[i][2]; v.w = acc[i][3];
        *(float4*)&out[rbase + tx * 4] = v;
    }
}

extern "C" void kernel_launch(void* const* d_in, const int* in_sizes, int n_in,
                              void* d_out, int out_size, void* d_ws, size_t ws_size,
                              hipStream_t stream) {
    const float* X  = (const float*)d_in[0];
    // d_in[1] = attention_mask: exactly causal; applied analytically.
    const float* Wq = (const float*)d_in[2];
    const float* bq = (const float*)d_in[3];
    const float* Wk = (const float*)d_in[4];
    const float* bk = (const float*)d_in[5];
    const float* Wv = (const float*)d_in[6];
    const float* bv = (const float*)d_in[7];
    const float* Wo = (const float*)d_in[8];
    float* out = (float*)d_out;

    char* ws = (char*)d_ws;
    ushort_t* qbuf = (ushort_t*)ws;                               // 3,670,016 bf16
    ushort_t* kbuf = qbuf + (size_t)BATCH * NH  * SEQ * HD;       //   524,288 bf16
    ushort_t* vbuf = kbuf + (size_t)BATCH * NKV * SEQ * HD;       //   524,288 bf16
    float*    abuf = (float*)(ws + 2 * ((size_t)BATCH * NH * SEQ * HD
                                      + 2 * (size_t)BATCH * NKV * SEQ * HD));

    qkv_kernel<<<dim3(64, 18), dim3(16, 16), 0, stream>>>(
        X, Wq, bq, Wk, bk, Wv, bv, qbuf, kbuf, vbuf);
    attn_kernel<<<dim3(16, NH, BATCH), 256, 0, stream>>>(
        qbuf, kbuf, vbuf, abuf);
    oproj_kernel<<<dim3(64, 14), dim3(16, 16), 0, stream>>>(
        abuf, Wo, out);
}

// Round 5
// 212.852 us; speedup vs baseline: 9.1780x; 3.5743x over previous
//
#include <hip/hip_runtime.h>
#include <hip/hip_bf16.h>
#include <math.h>

#define NH 14
#define NKV 2
#define HD 64
#define HID 896
#define SEQ 2048
#define BATCH 2

typedef __attribute__((ext_vector_type(8))) short short8;
typedef __attribute__((ext_vector_type(4))) float f32x4;
typedef unsigned short ushort_t;

__device__ __forceinline__ unsigned short f2b(float f) {
    unsigned int u = __float_as_uint(f);
    unsigned int r = (u + 0x7fffu + ((u >> 16) & 1u)) >> 16;   // RNE
    return (unsigned short)r;
}

// ---------------------------------------------------------------------------
// Prep A: X fp32 [4096,896] -> bf16 same layout. 8 elems/thread.
// ---------------------------------------------------------------------------
__global__ __launch_bounds__(256) void xcast_kernel(
    const float* __restrict__ X, ushort_t* __restrict__ Xb)
{
    size_t i = ((size_t)blockIdx.x * 256 + threadIdx.x) * 8;
    float4 a = *(const float4*)(X + i);
    float4 b = *(const float4*)(X + i + 4);
    short8 o;
    o[0] = f2b(a.x); o[1] = f2b(a.y); o[2] = f2b(a.z); o[3] = f2b(a.w);
    o[4] = f2b(b.x); o[5] = f2b(b.y); o[6] = f2b(b.z); o[7] = f2b(b.w);
    *(short8*)(Xb + i) = o;
}

// ---------------------------------------------------------------------------
// Prep B: weight transpose+cast. W [896][N] fp32 -> WT [n][k] bf16.
// z: 0=Wq->rows 0..895 of WqkvT, 1=Wk->rows 896.., 2=Wv->rows 1024.., 3=Wo->WoT.
// ---------------------------------------------------------------------------
__global__ __launch_bounds__(256) void wtrans_kernel(
    const float* __restrict__ Wq, const float* __restrict__ Wk,
    const float* __restrict__ Wv, const float* __restrict__ Wo,
    ushort_t* __restrict__ WqkvT, ushort_t* __restrict__ WoT)
{
    __shared__ float tile[32][33];
    const int tx = threadIdx.x, ty = threadIdx.y;   // block (32,8)
    const int z = blockIdx.z;
    const float* src; ushort_t* dst; int N, rowoff;
    if      (z == 0) { src = Wq; dst = WqkvT; N = HID; rowoff = 0;    }
    else if (z == 1) { src = Wk; dst = WqkvT; N = 128; rowoff = 896;  }
    else if (z == 2) { src = Wv; dst = WqkvT; N = 128; rowoff = 1024; }
    else             { src = Wo; dst = WoT;   N = HID; rowoff = 0;    }
    const int k0 = blockIdx.x * 32;
    const int n0 = blockIdx.y * 32;
    if (n0 >= N) return;
    #pragma unroll
    for (int i = 0; i < 4; ++i)
        tile[ty * 4 + i][tx] = src[(size_t)(k0 + ty * 4 + i) * N + n0 + tx];
    __syncthreads();
    #pragma unroll
    for (int i = 0; i < 4; ++i)
        dst[(size_t)(rowoff + n0 + ty * 4 + i) * HID + k0 + tx]
            = f2b(tile[tx][ty * 4 + i]);
}

// ---------------------------------------------------------------------------
// Kernel 1: QKV GEMM via bf16 MFMA + bias + RoPE epilogue.
// Xb [4096,896] bf16 @ WqkvT [1152,896] (n-major). grid (32, 18), 256 thr.
// Block tile 128x64; wave w: rows w*32..+31, 2 m-frags x 4 n-frags.
// LDS stride 40 shorts (80 B, conflict-free for b128 frag reads).
// ---------------------------------------------------------------------------
#define LDA 40
__global__ __launch_bounds__(256) void qkv_kernel(
    const ushort_t* __restrict__ Xb, const ushort_t* __restrict__ WqkvT,
    const float* __restrict__ bq, const float* __restrict__ bk,
    const float* __restrict__ bv,
    ushort_t* __restrict__ qbuf, ushort_t* __restrict__ kbuf,
    ushort_t* __restrict__ vbuf)
{
    __shared__ ushort_t Asb[128 * LDA];
    __shared__ ushort_t Bsb[64 * LDA];
    const int tid  = threadIdx.x;
    const int w    = tid >> 6;
    const int lane = tid & 63;
    const int quad = lane >> 4;
    const int l16  = lane & 15;
    const int m0 = blockIdx.x * 128;
    const int nt = blockIdx.y;
    const int nb = nt * 64;          // row base in WqkvT

    f32x4 acc[2][4];
    #pragma unroll
    for (int mf = 0; mf < 2; ++mf)
        #pragma unroll
        for (int nf = 0; nf < 4; ++nf) acc[mf][nf] = (f32x4){0.f, 0.f, 0.f, 0.f};

    for (int k0 = 0; k0 < HID; k0 += 32) {
        // A: 128x32 = 512 uint4, 2/thread
        #pragma unroll
        for (int j = 0; j < 2; ++j) {
            int u = tid + j * 256;
            int row = u >> 2, c8 = u & 3;
            *(short8*)&Asb[row * LDA + c8 * 8] =
                *(const short8*)(Xb + (size_t)(m0 + row) * HID + k0 + c8 * 8);
        }
        // B: 64x32 = 256 uint4, 1/thread
        {
            int row = tid >> 2, c8 = tid & 3;
            *(short8*)&Bsb[row * LDA + c8 * 8] =
                *(const short8*)(WqkvT + (size_t)(nb + row) * HID + k0 + c8 * 8);
        }
        __syncthreads();
        const ushort_t* Ab = &Asb[(w * 32 + l16) * LDA + quad * 8];
        short8 a0 = *(const short8*)Ab;
        short8 a1 = *(const short8*)(Ab + 16 * LDA);
        #pragma unroll
        for (int nf = 0; nf < 4; ++nf) {
            short8 bf = *(const short8*)&Bsb[(nf * 16 + l16) * LDA + quad * 8];
            acc[0][nf] = __builtin_amdgcn_mfma_f32_16x16x32_bf16(a0, bf, acc[0][nf], 0, 0, 0);
            acc[1][nf] = __builtin_amdgcn_mfma_f32_16x16x32_bf16(a1, bf, acc[1][nf], 0, 0, 0);
        }
        __syncthreads();
    }

    // epilogue: bias + RoPE + scatter. col d = f*16+l16; RoPE pairs (f, f+2).
    float bcol[4];
    #pragma unroll
    for (int f = 0; f < 4; ++f) {
        int d = f * 16 + l16;
        bcol[f] = (nt < 14) ? bq[nt * 64 + d]
                : (nt < 16) ? bk[(nt - 14) * 64 + d]
                            : bv[(nt - 16) * 64 + d];
    }
    const float lnth = 13.815510558f;  // ln(1e6)
    float if0 = expf(-((float)l16)        / 32.0f * lnth);
    float if1 = expf(-((float)(l16 + 16)) / 32.0f * lnth);

    #pragma unroll
    for (int mf = 0; mf < 2; ++mf)
        #pragma unroll
        for (int r = 0; r < 4; ++r) {
            int grow = m0 + w * 32 + mf * 16 + quad * 4 + r;
            int b = grow >> 11;
            int s = grow & 2047;
            float v0 = acc[mf][0][r] + bcol[0];
            float v1 = acc[mf][1][r] + bcol[1];
            float v2 = acc[mf][2][r] + bcol[2];
            float v3 = acc[mf][3][r] + bcol[3];
            if (nt < 16) {
                float s0, c0, s1, c1;
                sincosf((float)s * if0, &s0, &c0);
                sincosf((float)s * if1, &s1, &c1);
                float n0 = v0 * c0 - v2 * s0;
                float n2 = v2 * c0 + v0 * s0;
                float n1 = v1 * c1 - v3 * s1;
                float n3 = v3 * c1 + v1 * s1;
                v0 = n0; v1 = n1; v2 = n2; v3 = n3;
            }
            if (nt < 14) {
                ushort_t* dst = qbuf + ((size_t)(b * NH + nt) * SEQ + s) * HD;
                dst[l16]      = f2b(v0);
                dst[l16 + 16] = f2b(v1);
                dst[l16 + 32] = f2b(v2);
                dst[l16 + 48] = f2b(v3);
            } else if (nt < 16) {
                ushort_t* dst = kbuf + ((size_t)(b * NKV + nt - 14) * SEQ + s) * HD;
                dst[l16]      = f2b(v0);
                dst[l16 + 16] = f2b(v1);
                dst[l16 + 32] = f2b(v2);
                dst[l16 + 48] = f2b(v3);
            } else {
                ushort_t* dst = vbuf + (size_t)(b * NKV + nt - 16) * HD * SEQ + s;
                dst[(size_t)(l16)      * SEQ] = f2b(v0);
                dst[(size_t)(l16 + 16) * SEQ] = f2b(v1);
                dst[(size_t)(l16 + 32) * SEQ] = f2b(v2);
                dst[(size_t)(l16 + 48) * SEQ] = f2b(v3);
            }
        }
}

// ---------------------------------------------------------------------------
// Kernel 2: causal flash attention via bf16 MFMA (unchanged from R4 except
// bf16 output to abuf [4096][896]).
// ---------------------------------------------------------------------------
#define LDP 72
__global__ __launch_bounds__(256) void attn_kernel(
    const ushort_t* __restrict__ qbuf, const ushort_t* __restrict__ kbuf,
    const ushort_t* __restrict__ vbuf, ushort_t* __restrict__ abuf)
{
    __shared__ ushort_t Ks[64 * LDP];
    __shared__ ushort_t Vt[64 * LDP];
    __shared__ ushort_t Ps[4][16 * LDP];

    const int tid  = threadIdx.x;
    const int w    = tid >> 6;
    const int lane = tid & 63;
    const int quad = lane >> 4;
    const int l16  = lane & 15;
    const int bi = blockIdx.x;
    const int h  = blockIdx.y;
    const int b  = blockIdx.z;
    const int kvh = h / (NH / NKV);

    const ushort_t* kb_h = kbuf + (size_t)(b * NKV + kvh) * SEQ * HD;
    const ushort_t* vt_h = vbuf + (size_t)(b * NKV + kvh) * HD * SEQ;

    for (int pass = 0; pass < 2; ++pass) {
        const int qt = pass ? (31 - bi) : bi;

        const ushort_t* qrow =
            qbuf + ((size_t)((b * NH + h) * SEQ) + qt * 64 + w * 16 + l16) * HD;
        short8 qf0 = *(const short8*)(qrow + quad * 8);
        short8 qf1 = *(const short8*)(qrow + 32 + quad * 8);

        f32x4 O[4];
        float m_i[4], l_i[4];
        #pragma unroll
        for (int n = 0; n < 4; ++n) O[n] = (f32x4){0.f, 0.f, 0.f, 0.f};
        #pragma unroll
        for (int r = 0; r < 4; ++r) { m_i[r] = -1e30f; l_i[r] = 0.0f; }

        for (int kt = 0; kt <= qt; ++kt) {
            __syncthreads();
            for (int i = tid; i < 512; i += 256) {
                int row = i >> 3, c8 = i & 7;
                *(short8*)&Ks[row * LDP + c8 * 8] =
                    *(const short8*)(kb_h + ((size_t)(kt * 64 + row)) * HD + c8 * 8);
                *(short8*)&Vt[row * LDP + c8 * 8] =
                    *(const short8*)(vt_h + (size_t)row * SEQ + kt * 64 + c8 * 8);
            }
            __syncthreads();

            f32x4 S[4];
            #pragma unroll
            for (int f = 0; f < 4; ++f) {
                S[f] = (f32x4){0.f, 0.f, 0.f, 0.f};
                short8 kf0 = *(const short8*)&Ks[(f * 16 + l16) * LDP + quad * 8];
                short8 kf1 = *(const short8*)&Ks[(f * 16 + l16) * LDP + 32 + quad * 8];
                S[f] = __builtin_amdgcn_mfma_f32_16x16x32_bf16(qf0, kf0, S[f], 0, 0, 0);
                S[f] = __builtin_amdgcn_mfma_f32_16x16x32_bf16(qf1, kf1, S[f], 0, 0, 0);
            }

            const bool diag = (kt == qt);
            float sc[4][4];
            #pragma unroll
            for (int f = 0; f < 4; ++f)
                #pragma unroll
                for (int r = 0; r < 4; ++r) {
                    float v = S[f][r] * 0.125f;
                    if (diag && (f * 16 + l16) > (w * 16 + quad * 4 + r)) v = -1e30f;
                    sc[f][r] = v;
                }

            float pm[4];
            #pragma unroll
            for (int r = 0; r < 4; ++r)
                pm[r] = fmaxf(fmaxf(sc[0][r], sc[1][r]), fmaxf(sc[2][r], sc[3][r]));
            #pragma unroll
            for (int off = 1; off < 16; off <<= 1)
                #pragma unroll
                for (int r = 0; r < 4; ++r)
                    pm[r] = fmaxf(pm[r], __shfl_xor(pm[r], off));

            float alpha[4], psum[4];
            #pragma unroll
            for (int r = 0; r < 4; ++r) {
                float mnew = fmaxf(m_i[r], pm[r]);
                alpha[r] = __expf(m_i[r] - mnew);
                m_i[r] = mnew;
                psum[r] = 0.0f;
            }
            #pragma unroll
            for (int f = 0; f < 4; ++f)
                #pragma unroll
                for (int r = 0; r < 4; ++r) {
                    float p = __expf(sc[f][r] - m_i[r]);
                    sc[f][r] = p;
                    psum[r] += p;
                }
            #pragma unroll
            for (int off = 1; off < 16; off <<= 1)
                #pragma unroll
                for (int r = 0; r < 4; ++r)
                    psum[r] += __shfl_xor(psum[r], off);
            #pragma unroll
            for (int r = 0; r < 4; ++r)
                l_i[r] = l_i[r] * alpha[r] + psum[r];
            #pragma unroll
            for (int n = 0; n < 4; ++n)
                #pragma unroll
                for (int r = 0; r < 4; ++r)
                    O[n][r] *= alpha[r];

            #pragma unroll
            for (int f = 0; f < 4; ++f)
                #pragma unroll
                for (int r = 0; r < 4; ++r)
                    Ps[w][(quad * 4 + r) * LDP + f * 16 + l16] = f2b(sc[f][r]);
            short8 pa0 = *(const short8*)&Ps[w][l16 * LDP + quad * 8];
            short8 pa1 = *(const short8*)&Ps[w][l16 * LDP + 32 + quad * 8];

            #pragma unroll
            for (int n = 0; n < 4; ++n) {
                short8 vf0 = *(const short8*)&Vt[(n * 16 + l16) * LDP + quad * 8];
                short8 vf1 = *(const short8*)&Vt[(n * 16 + l16) * LDP + 32 + quad * 8];
                O[n] = __builtin_amdgcn_mfma_f32_16x16x32_bf16(pa0, vf0, O[n], 0, 0, 0);
                O[n] = __builtin_amdgcn_mfma_f32_16x16x32_bf16(pa1, vf1, O[n], 0, 0, 0);
            }
        }

        float inv[4];
        #pragma unroll
        for (int r = 0; r < 4; ++r) inv[r] = 1.0f / l_i[r];
        #pragma unroll
        for (int n = 0; n < 4; ++n)
            #pragma unroll
            for (int r = 0; r < 4; ++r) {
                int rowg = qt * 64 + w * 16 + quad * 4 + r;
                abuf[(size_t)(b * SEQ + rowg) * HID + h * HD + n * 16 + l16]
                    = f2b(O[n][r] * inv[r]);
            }
    }
}

// ---------------------------------------------------------------------------
// Kernel 3: output projection via bf16 MFMA. abuf bf16 @ WoT bf16 -> out fp32.
// Same tiling as qkv, plain fp32 store epilogue. grid (32, 14).
// ---------------------------------------------------------------------------
__global__ __launch_bounds__(256) void oproj_kernel(
    const ushort_t* __restrict__ A, const ushort_t* __restrict__ WoT,
    float* __restrict__ out)
{
    __shared__ ushort_t Asb[128 * LDA];
    __shared__ ushort_t Bsb[64 * LDA];
    const int tid  = threadIdx.x;
    const int w    = tid >> 6;
    const int lane = tid & 63;
    const int quad = lane >> 4;
    const int l16  = lane & 15;
    const int m0 = blockIdx.x * 128;
    const int n0 = blockIdx.y * 64;

    f32x4 acc[2][4];
    #pragma unroll
    for (int mf = 0; mf < 2; ++mf)
        #pragma unroll
        for (int nf = 0; nf < 4; ++nf) acc[mf][nf] = (f32x4){0.f, 0.f, 0.f, 0.f};

    for (int k0 = 0; k0 < HID; k0 += 32) {
        #pragma unroll
        for (int j = 0; j < 2; ++j) {
            int u = tid + j * 256;
            int row = u >> 2, c8 = u & 3;
            *(short8*)&Asb[row * LDA + c8 * 8] =
                *(const short8*)(A + (size_t)(m0 + row) * HID + k0 + c8 * 8);
        }
        {
            int row = tid >> 2, c8 = tid & 3;
            *(short8*)&Bsb[row * LDA + c8 * 8] =
                *(const short8*)(WoT + (size_t)(n0 + row) * HID + k0 + c8 * 8);
        }
        __syncthreads();
        const ushort_t* Ab = &Asb[(w * 32 + l16) * LDA + quad * 8];
        short8 a0 = *(const short8*)Ab;
        short8 a1 = *(const short8*)(Ab + 16 * LDA);
        #pragma unroll
        for (int nf = 0; nf < 4; ++nf) {
            short8 bf = *(const short8*)&Bsb[(nf * 16 + l16) * LDA + quad * 8];
            acc[0][nf] = __builtin_amdgcn_mfma_f32_16x16x32_bf16(a0, bf, acc[0][nf], 0, 0, 0);
            acc[1][nf] = __builtin_amdgcn_mfma_f32_16x16x32_bf16(a1, bf, acc[1][nf], 0, 0, 0);
        }
        __syncthreads();
    }

    #pragma unroll
    for (int mf = 0; mf < 2; ++mf)
        #pragma unroll
        for (int r = 0; r < 4; ++r) {
            size_t rbase = (size_t)(m0 + w * 32 + mf * 16 + quad * 4 + r) * HID + n0;
            #pragma unroll
            for (int f = 0; f < 4; ++f)
                out[rbase + f * 16 + l16] = acc[mf][f][r];
        }
}

extern "C" void kernel_launch(void* const* d_in, const int* in_sizes, int n_in,
                              void* d_out, int out_size, void* d_ws, size_t ws_size,
                              hipStream_t stream) {
    const float* X  = (const float*)d_in[0];
    // d_in[1] = attention_mask: exactly causal; applied analytically.
    const float* Wq = (const float*)d_in[2];
    const float* bq = (const float*)d_in[3];
    const float* Wk = (const float*)d_in[4];
    const float* bk = (const float*)d_in[5];
    const float* Wv = (const float*)d_in[6];
    const float* bv = (const float*)d_in[7];
    const float* Wo = (const float*)d_in[8];
    float* out = (float*)d_out;

    ushort_t* ws    = (ushort_t*)d_ws;
    ushort_t* Xb    = ws;                   // 3,670,016
    ushort_t* WqkvT = Xb    + 3670016;      // 1,032,192 (rows: 896 q | 128 k | 128 v)
    ushort_t* WoT   = WqkvT + 1032192;      //   802,816
    ushort_t* qbuf  = WoT   + 802816;       // 3,670,016
    ushort_t* kbuf  = qbuf  + 3670016;      //   524,288
    ushort_t* vbuf  = kbuf  + 524288;       //   524,288
    ushort_t* abufb = vbuf  + 524288;       // 3,670,016   (total ~26.5 MiB)

    xcast_kernel<<<dim3(1792), 256, 0, stream>>>(X, Xb);
    wtrans_kernel<<<dim3(28, 28, 4), dim3(32, 8), 0, stream>>>(
        Wq, Wk, Wv, Wo, WqkvT, WoT);
    qkv_kernel<<<dim3(32, 18), 256, 0, stream>>>(
        Xb, WqkvT, bq, bk, bv, qbuf, kbuf, vbuf);
    attn_kernel<<<dim3(16, NH, BATCH), 256, 0, stream>>>(
        qbuf, kbuf, vbuf, abufb);
    oproj_kernel<<<dim3(32, 14), 256, 0, stream>>>(
        abufb, WoT, out);
}